// Round 6
// baseline (427.934 us; speedup 1.0000x reference)
//
#include <hip/hip_runtime.h>
#include <math.h>

#define NS 32          // NSAMPLE
#define WPB 4          // waves per block (= queries per block in phase 1)
#define SCAN0 2048     // prefix length scanned in phase 1
#define TSTRIDE 36     // transpose j-stride in dwords (mult of 4 -> b128-aligned)
#define MAXBLK 2048    // co-residency capacity: 8 blk/CU (19.6KB LDS) x 256 CU

// ---------------------------------------------------------------------------
// Per-WAVE output epilogue for one query m (round-1 proven form, plain
// stores). Wave-internal LDS transpose, XOR-swizzled (2-way banked = free).
// ---------------------------------------------------------------------------
__device__ __forceinline__ void write_query(
    int m, int bb, bool empty, int lane,
    const int* sIdxW, float* sT,
    const float* __restrict__ xyz, const float* __restrict__ new_xyz,
    const float* __restrict__ new_xyz_r, const float* __restrict__ features,
    float real_t, float* __restrict__ out, int N_per, int C, int M_tot)
{
#pragma clang fp contract(off)
    const float* xb = xyz + (size_t)bb * N_per * 3;
    const int    j  = lane & 31;
    const size_t nf_base = (size_t)m * (3 + C) * NS;
    float* wout = out + (size_t)M_tot * (3 + C) * NS;
    float* iout = wout + (size_t)M_tot * NS;

    if (lane < NS) {
        const float qx = new_xyz[(size_t)m * 3 + 0];
        const float qy = new_xyz[(size_t)m * 3 + 1];
        const float qz = new_xyz[(size_t)m * 3 + 2];
        const float r_orig = new_xyz_r[m];
        const int pj = empty ? 0 : sIdxW[j];
        float gx = 0.f, gy = 0.f, gz = 0.f;
        if (!empty) {
            gx = xb[(size_t)pj * 3 + 0] - qx;
            gy = xb[(size_t)pj * 3 + 1] - qy;
            gz = xb[(size_t)pj * 3 + 2] - qz;
        }
        float d2 = gx * gx;
        d2 = d2 + gy * gy;
        d2 = d2 + gz * gz;
        float dist = sqrtf(d2);
        float wt = 1.0f / (1.0f + expf((dist - r_orig) / real_t)); // 1-sigmoid
        out[nf_base + 0 * NS + j] = gx;
        out[nf_base + 1 * NS + j] = gy;
        out[nf_base + 2 * NS + j] = gz;
        wout[(size_t)m * NS + j] = wt;
        iout[(size_t)m * NS + j] = (float)pj;   // f32 buffer; idx exact
    }

    const float* fb = features + (size_t)bb * N_per * C;
    int c0 = 0;
    for (; c0 + 32 <= C; c0 += 32) {
        const int k  = lane & 7;                 // col group (4 channels)
        const int f4 = 4 * (k & 3);              // XOR swizzle
        #pragma unroll
        for (int t = 0; t < 4; ++t) {
            const int r  = 8 * t + (lane >> 3);  // sample slot
            const int pj = empty ? 0 : sIdxW[r];
            float4 v = make_float4(0.f, 0.f, 0.f, 0.f);
            if (!empty) v = *(const float4*)(fb + (size_t)pj * C + c0 + 4 * k);
            const int rs = r ^ f4;
            sT[(4 * k + 0) * TSTRIDE + rs] = v.x;
            sT[(4 * k + 1) * TSTRIDE + rs] = v.y;
            sT[(4 * k + 2) * TSTRIDE + rs] = v.z;
            sT[(4 * k + 3) * TSTRIDE + rs] = v.w;
        }
        // wave-internal LDS dependency: lockstep + lgkmcnt, no barrier
        const int jg = lane & 7;                 // group of 4 samples
        #pragma unroll
        for (int s2 = 0; s2 < 4; ++s2) {
            const int ch = 8 * s2 + (lane >> 3); // channel within pass
            const int jb = (4 * jg) ^ (4 * ((ch >> 2) & 3));
            float4 w = *(const float4*)&sT[ch * TSTRIDE + jb];
            *(float4*)&out[nf_base + (size_t)(3 + c0 + ch) * NS + 4 * jg] = w;
        }
    }
    if (c0 < C) {   // tail for C % 32 != 0 (dead for C=64)
        const int h  = lane >> 5;
        const int pj = empty ? 0 : sIdxW[j];
        const float* frow = fb + (size_t)pj * C;
        for (int c = c0 + h; c < C; c += 2) {
            float v = empty ? 0.f : frow[c];
            out[nf_base + (size_t)(3 + c) * NS + j] = v;
        }
    }
}

// ---------------------------------------------------------------------------
// Wave-level in-index-order ball scan of [rb, re); scalar 256-pt chunks
// (proven fastest: 128-chunk and per-lane-4pt variants both regressed).
// ---------------------------------------------------------------------------
__device__ __forceinline__ int scan_range(
    const float* __restrict__ xb, float qx, float qy, float qz, float er2,
    int rb, int re, int lane, unsigned long long lt, int* hits)
{
#pragma clang fp contract(off)          // keep d2 < r^2 bit-exact vs numpy
    int cnt = 0;
    for (int base = rb; base < re; base += 256) {
        float d2k[4];
        #pragma unroll
        for (int k = 0; k < 4; ++k) {
            int p = base + k * 64 + lane;
            int pc = (p < re) ? p : (re - 1);
            const float* pp = xb + (size_t)pc * 3;
            float dx = pp[0] - qx, dy = pp[1] - qy, dz = pp[2] - qz;
            float d2 = dx * dx;
            d2 = d2 + dy * dy;          // numpy left-fold order
            d2 = d2 + dz * dz;
            d2k[k] = (p < re) ? d2 : 1e30f;
        }
        #pragma unroll
        for (int k = 0; k < 4; ++k) {
            bool hit = d2k[k] < er2;    // strict <
            unsigned long long msk = __ballot(hit);
            if (hit) {
                int slot = cnt + (int)__popcll(msk & lt);
                if (slot < NS) hits[slot] = base + k * 64 + lane;
            }
            cnt += (int)__popcll(msk);  // wave-uniform
        }
        if (cnt >= NS) break;           // wave-uniform
    }
    return cnt;
}

// ---------------------------------------------------------------------------
// Work-stealing fused kernel.
// Phase 1 (grid-stride): per-wave prefix scan of first SCAN0 points; finished
// queries write immediately (barrier-free wave epilogue); stragglers are
// PUSHED to a global list (atomicAdd slot + atomicExch publish into a
// -1-poisoned array).
// Phase 2: after done-counter reaches gridDim.x's worth of producers, ALL
// blocks POP stragglers (atomic pop; spin until entry published or all
// producers done). Each popped query: 4-wave quarter-split full [0,N) rescan,
// exact in-order merge, wave-0 epilogue. Spinning is deadlock-free because
// grid <= MAXBLK co-resident blocks (launch_bounds(256,8) caps VGPR at 64;
// LDS 19.6KB -> 8 blocks/CU).
// ---------------------------------------------------------------------------
__global__ __launch_bounds__(256, 8) void qgd_W(
    const float* __restrict__ xyz, const float* __restrict__ new_xyz,
    const float* __restrict__ new_xyz_r, const float* __restrict__ features,
    const float* __restrict__ tdec, float* __restrict__ out,
    int* __restrict__ ws,
    int N_per, int M_per, int C, int M_tot)
{
#pragma clang fp contract(off)
    __shared__ __align__(16) float sBuf[WPB * 32 * TSTRIDE];
    __shared__ int sIdx[WPB][NS];    // phase-1 prefix hits (per wave)
    __shared__ int sH[WPB][NS];      // phase-2 per-wave rescan hits
    __shared__ int sC[WPB];          // phase-2 per-wave counts (capped NS)
    __shared__ int sM[NS];           // merged idx list
    __shared__ int sTot;
    __shared__ int sMq;              // popped straggler query (broadcast)

    int* push = ws + 0;
    int* pop  = ws + 1;
    int* done = ws + 2;
    int* list = ws + 4;

    const int lane = threadIdx.x & 63;
    const int wv   = threadIdx.x >> 6;
    const unsigned long long lt = (1ull << lane) - 1ull;
    const float real_t = 0.1f * tdec[0];
    const int scan0 = (SCAN0 < N_per) ? SCAN0 : N_per;
    const int ngroups = (M_tot + WPB - 1) / WPB;

    // ---------------- phase 1: grid-stride prefix scans + produce ----------
    for (int g = blockIdx.x; g < ngroups; g += gridDim.x) {
        const int m = g * WPB + wv;
        if (m < M_tot) {
            const int bb = m / M_per;
            const float* xb = xyz + (size_t)bb * N_per * 3;
            const float qx = new_xyz[(size_t)m * 3 + 0];
            const float qy = new_xyz[(size_t)m * 3 + 1];
            const float qz = new_xyz[(size_t)m * 3 + 2];
            const float er  = new_xyz_r[m] + real_t * 5.0f;
            const float er2 = er * er;

            int cnt = scan_range(xb, qx, qy, qz, er2, 0, scan0, lane, lt,
                                 sIdx[wv]);
            if (cnt >= NS) {
                write_query(m, bb, /*empty=*/false, lane, sIdx[wv],
                            sBuf + wv * (32 * TSTRIDE),
                            xyz, new_xyz, new_xyz_r, features, real_t, out,
                            N_per, C, M_tot);
            } else if (lane == 0) {
                int pos = atomicAdd(push, 1);
                atomicExch(&list[pos], m);   // device-visible publish
            }
        }
    }
    // Each wave's atomics drain before it passes the barrier (compiler emits
    // vmcnt(0) before s_barrier), so done++ below is safely ordered after
    // ALL this block's publishes.
    __syncthreads();
    if (threadIdx.x == 0) {
        __threadfence();
        atomicAdd(done, 1);
    }

    // ---------------- phase 2: work-stealing consume ----------------
    const int nprod = gridDim.x;
    for (;;) {
        if (threadIdx.x == 0) {
            int mq = -1;
            int i = atomicAdd(pop, 1);
            if (i >= M_tot) {
                mq = -1;                         // beyond capacity: exit
            } else {
                for (;;) {
                    mq = atomicAdd(&list[i], 0); // atomic read
                    if (mq >= 0) break;
                    int d = atomicAdd(done, 0);
                    if (d >= nprod) {
                        int p = atomicAdd(push, 0);
                        if (i >= p) { mq = -1; break; }  // list exhausted
                    }
                    __builtin_amdgcn_s_sleep(8);
                }
            }
            sMq = mq;
        }
        __syncthreads();                 // sMq visible; prev iter's sH/sM free
        const int mq = sMq;
        if (mq < 0) break;

        const int bbs = mq / M_per;
        const float* xbs = xyz + (size_t)bbs * N_per * 3;
        const float qx = new_xyz[(size_t)mq * 3 + 0];
        const float qy = new_xyz[(size_t)mq * 3 + 1];
        const float qz = new_xyz[(size_t)mq * 3 + 2];
        const float er  = new_xyz_r[mq] + real_t * 5.0f;
        const float er2 = er * er;

        // quarter-split full rescan [0, N_per): exact first-NS via merge
        const int rb = (int)(((long long)N_per * wv) / WPB);
        const int re = (int)(((long long)N_per * (wv + 1)) / WPB);
        int c2 = scan_range(xbs, qx, qy, qz, er2, rb, re, lane, lt, sH[wv]);
        if (lane == 0) sC[wv] = (c2 < NS) ? c2 : NS;
        __syncthreads();                 // sH/sC ready

        if (threadIdx.x < NS) {          // in-order merge (wave 0 lanes)
            const int j  = threadIdx.x;
            const int c0 = sC[0], c1 = sC[1], c2_ = sC[2], c3 = sC[3];
            const int o1 = c0, o2 = c0 + c1, o3 = o2 + c2_;
            const int tot = o3 + c3;
            int v = 0;
            if (j < tot) {
                if      (j >= o3) v = sH[3][j - o3];
                else if (j >= o2) v = sH[2][j - o2];
                else if (j >= o1) v = sH[1][j - o1];
                else              v = sH[0][j];
            }
            int first = 0;
            if      (c0  > 0) first = sH[0][0];
            else if (c1  > 0) first = sH[1][0];
            else if (c2_ > 0) first = sH[2][0];
            else if (c3  > 0) first = sH[3][0];
            sM[j] = (tot == 0) ? 0 : ((j < tot) ? v : first);
            if (j == 0) sTot = tot;
        }
        __syncthreads();                 // sM/sTot ready

        if (wv == 0) {                   // wave-0 epilogue; others loop to pop
            write_query(mq, bbs, /*empty=*/(sTot == 0), lane, sM, sBuf,
                        xyz, new_xyz, new_xyz_r, features, real_t, out,
                        N_per, C, M_tot);
        }
        // next iteration's first __syncthreads guards sH/sM reuse
    }
}

extern "C" void kernel_launch(void* const* d_in, const int* in_sizes, int n_in,
                              void* d_out, int out_size, void* d_ws, size_t ws_size,
                              hipStream_t stream) {
    const float* xyz       = (const float*)d_in[0];
    const float* new_xyz   = (const float*)d_in[2];
    const float* new_xyz_r = (const float*)d_in[3];
    const float* features  = (const float*)d_in[5];
    const float* tdec      = (const float*)d_in[6];

    const int B     = in_sizes[1];
    const int N_tot = in_sizes[0] / 3;
    const int M_tot = in_sizes[2] / 3;
    const int C     = in_sizes[5] / N_tot;
    const int N_per = N_tot / B;
    const int M_per = M_tot / B;

    float* out = (float*)d_out;
    int*   ws  = (int*)d_ws;

    // ws layout: [0]=push, [1]=pop, [2]=done, [3]=pad, [4..4+M_tot)=list
    hipMemsetAsync(ws, 0, 16, stream);
    hipMemsetAsync(ws + 4, 0xFF, (size_t)M_tot * sizeof(int), stream);

    const int ngroups = (M_tot + WPB - 1) / WPB;
    const int blocks  = (ngroups < MAXBLK) ? ngroups : MAXBLK;
    qgd_W<<<blocks, 256, 0, stream>>>(xyz, new_xyz, new_xyz_r, features,
                                      tdec, out, ws,
                                      N_per, M_per, C, M_tot);
}

// Round 7
// 118.369 us; speedup vs baseline: 3.6152x; 3.6152x over previous
//
#include <hip/hip_runtime.h>
#include <math.h>

#define NS 32          // NSAMPLE
#define WPB 4          // waves per block (= queries per block)
#define SCAN0 2048     // prefix length scanned in phase 1
#define TSTRIDE 36     // transpose j-stride in dwords (mult of 4 -> b128-aligned)

// ---------------------------------------------------------------------------
// Per-WAVE output epilogue for one query m (round-1 proven form, plain
// stores). Wave-internal LDS transpose, XOR-swizzled (2-way banked = free).
// ---------------------------------------------------------------------------
__device__ __forceinline__ void write_query(
    int m, int bb, bool empty, int lane,
    const int* sIdxW, float* sT,
    const float* __restrict__ xyz, const float* __restrict__ new_xyz,
    const float* __restrict__ new_xyz_r, const float* __restrict__ features,
    float real_t, float* __restrict__ out, int N_per, int C, int M_tot)
{
#pragma clang fp contract(off)
    const float* xb = xyz + (size_t)bb * N_per * 3;
    const int    j  = lane & 31;
    const size_t nf_base = (size_t)m * (3 + C) * NS;
    float* wout = out + (size_t)M_tot * (3 + C) * NS;
    float* iout = wout + (size_t)M_tot * NS;

    if (lane < NS) {
        const float qx = new_xyz[(size_t)m * 3 + 0];
        const float qy = new_xyz[(size_t)m * 3 + 1];
        const float qz = new_xyz[(size_t)m * 3 + 2];
        const float r_orig = new_xyz_r[m];
        const int pj = empty ? 0 : sIdxW[j];
        float gx = 0.f, gy = 0.f, gz = 0.f;
        if (!empty) {
            gx = xb[(size_t)pj * 3 + 0] - qx;
            gy = xb[(size_t)pj * 3 + 1] - qy;
            gz = xb[(size_t)pj * 3 + 2] - qz;
        }
        float d2 = gx * gx;
        d2 = d2 + gy * gy;
        d2 = d2 + gz * gz;
        float dist = sqrtf(d2);
        float wt = 1.0f / (1.0f + expf((dist - r_orig) / real_t)); // 1-sigmoid
        out[nf_base + 0 * NS + j] = gx;
        out[nf_base + 1 * NS + j] = gy;
        out[nf_base + 2 * NS + j] = gz;
        wout[(size_t)m * NS + j] = wt;
        iout[(size_t)m * NS + j] = (float)pj;   // f32 buffer; idx exact
    }

    const float* fb = features + (size_t)bb * N_per * C;
    int c0 = 0;
    for (; c0 + 32 <= C; c0 += 32) {
        const int k  = lane & 7;                 // col group (4 channels)
        const int f4 = 4 * (k & 3);              // XOR swizzle
        #pragma unroll
        for (int t = 0; t < 4; ++t) {
            const int r  = 8 * t + (lane >> 3);  // sample slot
            const int pj = empty ? 0 : sIdxW[r];
            float4 v = make_float4(0.f, 0.f, 0.f, 0.f);
            if (!empty) v = *(const float4*)(fb + (size_t)pj * C + c0 + 4 * k);
            const int rs = r ^ f4;
            sT[(4 * k + 0) * TSTRIDE + rs] = v.x;
            sT[(4 * k + 1) * TSTRIDE + rs] = v.y;
            sT[(4 * k + 2) * TSTRIDE + rs] = v.z;
            sT[(4 * k + 3) * TSTRIDE + rs] = v.w;
        }
        // wave-internal LDS dependency: lockstep + lgkmcnt, no barrier
        const int jg = lane & 7;                 // group of 4 samples
        #pragma unroll
        for (int s2 = 0; s2 < 4; ++s2) {
            const int ch = 8 * s2 + (lane >> 3); // channel within pass
            const int jb = (4 * jg) ^ (4 * ((ch >> 2) & 3));
            float4 w = *(const float4*)&sT[ch * TSTRIDE + jb];
            *(float4*)&out[nf_base + (size_t)(3 + c0 + ch) * NS + 4 * jg] = w;
        }
    }
    if (c0 < C) {   // tail for C % 32 != 0 (dead for C=64)
        const int h  = lane >> 5;
        const int pj = empty ? 0 : sIdxW[j];
        const float* frow = fb + (size_t)pj * C;
        for (int c = c0 + h; c < C; c += 2) {
            float v = empty ? 0.f : frow[c];
            out[nf_base + (size_t)(3 + c) * NS + j] = v;
        }
    }
}

// ---------------------------------------------------------------------------
// 4-wave COOPERATIVE epilogue (phase-2 stragglers only): waves 0..2 split the
// 32-channel feature passes (each wave uses its OWN LDS tile -> no cross-wave
// dependency, no barrier); wave 3 writes the xyz/weight/idx header + any
// C%32 scalar tail. Halves the single-wave epilogue latency chain that sits
// on the straggler critical path.
// ---------------------------------------------------------------------------
__device__ __forceinline__ void write_query_coop(
    int m, int bb, bool empty, int lane, int wv,
    const int* sIdxW, float* sT,
    const float* __restrict__ xyz, const float* __restrict__ new_xyz,
    const float* __restrict__ new_xyz_r, const float* __restrict__ features,
    float real_t, float* __restrict__ out, int N_per, int C, int M_tot)
{
#pragma clang fp contract(off)
    const size_t nf_base = (size_t)m * (3 + C) * NS;

    if (wv == 3) {
        const float* xb = xyz + (size_t)bb * N_per * 3;
        const int    j  = lane & 31;
        float* wout = out + (size_t)M_tot * (3 + C) * NS;
        float* iout = wout + (size_t)M_tot * NS;
        if (lane < NS) {
            const float qx = new_xyz[(size_t)m * 3 + 0];
            const float qy = new_xyz[(size_t)m * 3 + 1];
            const float qz = new_xyz[(size_t)m * 3 + 2];
            const float r_orig = new_xyz_r[m];
            const int pj = empty ? 0 : sIdxW[j];
            float gx = 0.f, gy = 0.f, gz = 0.f;
            if (!empty) {
                gx = xb[(size_t)pj * 3 + 0] - qx;
                gy = xb[(size_t)pj * 3 + 1] - qy;
                gz = xb[(size_t)pj * 3 + 2] - qz;
            }
            float d2 = gx * gx;
            d2 = d2 + gy * gy;
            d2 = d2 + gz * gz;
            float dist = sqrtf(d2);
            float wt = 1.0f / (1.0f + expf((dist - r_orig) / real_t));
            out[nf_base + 0 * NS + j] = gx;
            out[nf_base + 1 * NS + j] = gy;
            out[nf_base + 2 * NS + j] = gz;
            wout[(size_t)m * NS + j] = wt;
            iout[(size_t)m * NS + j] = (float)pj;
        }
        // scalar tail for C % 32 != 0 (dead for C=64)
        const int c0f = (C / 32) * 32;
        if (c0f < C) {
            const int h  = lane >> 5;
            const int pj = empty ? 0 : sIdxW[j];
            const float* frow = features + (size_t)bb * N_per * C + (size_t)pj * C;
            for (int c = c0f + h; c < C; c += 2) {
                float v = empty ? 0.f : frow[c];
                out[nf_base + (size_t)(3 + c) * NS + j] = v;
            }
        }
        return;
    }

    // waves 0..2: feature passes c0 = 32*wv, 32*wv+96, ... (own LDS tile)
    const float* fb = features + (size_t)bb * N_per * C;
    for (int c0 = 32 * wv; c0 + 32 <= C; c0 += 96) {
        const int k  = lane & 7;
        const int f4 = 4 * (k & 3);
        #pragma unroll
        for (int t = 0; t < 4; ++t) {
            const int r  = 8 * t + (lane >> 3);
            const int pj = empty ? 0 : sIdxW[r];
            float4 v = make_float4(0.f, 0.f, 0.f, 0.f);
            if (!empty) v = *(const float4*)(fb + (size_t)pj * C + c0 + 4 * k);
            const int rs = r ^ f4;
            sT[(4 * k + 0) * TSTRIDE + rs] = v.x;
            sT[(4 * k + 1) * TSTRIDE + rs] = v.y;
            sT[(4 * k + 2) * TSTRIDE + rs] = v.z;
            sT[(4 * k + 3) * TSTRIDE + rs] = v.w;
        }
        const int jg = lane & 7;
        #pragma unroll
        for (int s2 = 0; s2 < 4; ++s2) {
            const int ch = 8 * s2 + (lane >> 3);
            const int jb = (4 * jg) ^ (4 * ((ch >> 2) & 3));
            float4 w = *(const float4*)&sT[ch * TSTRIDE + jb];
            *(float4*)&out[nf_base + (size_t)(3 + c0 + ch) * NS + 4 * jg] = w;
        }
    }
}

// ---------------------------------------------------------------------------
// Wave-level in-index-order ball scan of [rb, re); scalar 256-pt chunks.
// Used in phase 1 where early exit after ~1 chunk is the common case.
// ---------------------------------------------------------------------------
__device__ __forceinline__ int scan_range(
    const float* __restrict__ xb, float qx, float qy, float qz, float er2,
    int rb, int re, int lane, unsigned long long lt, int* hits)
{
#pragma clang fp contract(off)          // keep d2 < r^2 bit-exact vs numpy
    int cnt = 0;
    for (int base = rb; base < re; base += 256) {
        float d2k[4];
        #pragma unroll
        for (int k = 0; k < 4; ++k) {
            int p = base + k * 64 + lane;
            int pc = (p < re) ? p : (re - 1);
            const float* pp = xb + (size_t)pc * 3;
            float dx = pp[0] - qx, dy = pp[1] - qy, dz = pp[2] - qz;
            float d2 = dx * dx;
            d2 = d2 + dy * dy;          // numpy left-fold order
            d2 = d2 + dz * dz;
            d2k[k] = (p < re) ? d2 : 1e30f;
        }
        #pragma unroll
        for (int k = 0; k < 4; ++k) {
            bool hit = d2k[k] < er2;    // strict <
            unsigned long long msk = __ballot(hit);
            if (hit) {
                int slot = cnt + (int)__popcll(msk & lt);
                if (slot < NS) hits[slot] = base + k * 64 + lane;
            }
            cnt += (int)__popcll(msk);  // wave-uniform
        }
        if (cnt >= NS) break;           // wave-uniform
    }
    return cnt;
}

// ---------------------------------------------------------------------------
// Deep variant for phase-2 straggler rescans: 512-pt chunks (8-deep unroll,
// 24 loads in flight per chain step). Stragglers rarely early-exit, so the
// coarser exit granularity is free and the latency chain halves (7 steps
// instead of 14 for a 3584-pt quarter).
// ---------------------------------------------------------------------------
__device__ __forceinline__ int scan_range_deep(
    const float* __restrict__ xb, float qx, float qy, float qz, float er2,
    int rb, int re, int lane, unsigned long long lt, int* hits)
{
#pragma clang fp contract(off)
    int cnt = 0;
    for (int base = rb; base < re; base += 512) {
        float d2k[8];
        #pragma unroll
        for (int k = 0; k < 8; ++k) {
            int p = base + k * 64 + lane;
            int pc = (p < re) ? p : (re - 1);
            const float* pp = xb + (size_t)pc * 3;
            float dx = pp[0] - qx, dy = pp[1] - qy, dz = pp[2] - qz;
            float d2 = dx * dx;
            d2 = d2 + dy * dy;          // numpy left-fold order
            d2 = d2 + dz * dz;
            d2k[k] = (p < re) ? d2 : 1e30f;
        }
        #pragma unroll
        for (int k = 0; k < 8; ++k) {
            bool hit = d2k[k] < er2;    // strict <
            unsigned long long msk = __ballot(hit);
            if (hit) {
                int slot = cnt + (int)__popcll(msk & lt);
                if (slot < NS) hits[slot] = base + k * 64 + lane;
            }
            cnt += (int)__popcll(msk);  // wave-uniform
        }
        if (cnt >= NS) break;           // wave-uniform
    }
    return cnt;
}

// ---------------------------------------------------------------------------
// Fused kernel (round-1 proven structure): phase 1 = per-wave prefix
// ball-query (first SCAN0 points); queries reaching NS hits write ALL their
// outputs immediately (per-wave epilogue, no barriers). Phase 2 = stragglers
// among the block's WPB queries finished by all 4 waves quarter-splitting
// ONLY the remaining [SCAN0, N) range (deep 512-pt chunks), exact in-order
// merge {prefix, w0..w3}, then a 4-wave cooperative epilogue.
// ---------------------------------------------------------------------------
__global__ __launch_bounds__(256) void qgd_F(
    const float* __restrict__ xyz, const float* __restrict__ new_xyz,
    const float* __restrict__ new_xyz_r, const float* __restrict__ features,
    const float* __restrict__ tdec, float* __restrict__ out,
    int N_per, int M_per, int C, int M_tot)
{
#pragma clang fp contract(off)
    __shared__ __align__(16) float sBuf[WPB * 32 * TSTRIDE];
    __shared__ int sIdx[WPB][NS];    // phase-1 prefix hits
    __shared__ int sH[WPB][NS];      // phase-2 per-wave continuation hits
    __shared__ int sCnt[WPB];        // phase-1 prefix count (< NS for stragglers)
    __shared__ int sStrag[WPB];      // straggler flag per wave
    __shared__ int sC[WPB];          // phase-2 per-wave counts (capped NS)
    __shared__ int sM[NS];           // merged idx list
    __shared__ int sTot;

    const int lane = threadIdx.x & 63;
    const int wv   = threadIdx.x >> 6;
    const int m    = blockIdx.x * WPB + wv;
    const bool valid = (m < M_tot);

    const float real_t = 0.1f * tdec[0];
    const unsigned long long lt = (1ull << lane) - 1ull;
    const int scan0 = (SCAN0 < N_per) ? SCAN0 : N_per;

    // ---------------- phase 1: per-wave prefix scan ----------------
    int cnt = 0;
    int bb = 0;
    if (valid) {
        bb = m / M_per;
        const float* xb = xyz + (size_t)bb * N_per * 3;
        const float qx = new_xyz[(size_t)m * 3 + 0];
        const float qy = new_xyz[(size_t)m * 3 + 1];
        const float qz = new_xyz[(size_t)m * 3 + 2];
        const float er  = new_xyz_r[m] + real_t * 5.0f;
        const float er2 = er * er;

        cnt = scan_range(xb, qx, qy, qz, er2, 0, scan0, lane, lt, sIdx[wv]);

        if (cnt >= NS) {
            write_query(m, bb, /*empty=*/false, lane, sIdx[wv],
                        sBuf + wv * (32 * TSTRIDE),
                        xyz, new_xyz, new_xyz_r, features, real_t, out,
                        N_per, C, M_tot);
        }
    }
    if (lane == 0) {
        sCnt[wv]   = cnt;                              // exact (< NS) when straggler
        sStrag[wv] = (valid && cnt < NS) ? 1 : 0;
    }
    __syncthreads();                 // sIdx/sCnt/sStrag ready; sBuf slices free

    // ---------------- phase 2: block-cooperative straggler finish ----------
    for (int s = 0; s < WPB; ++s) {
        if (!sStrag[s]) continue;    // uniform across block (same LDS word)

        const int ms  = blockIdx.x * WPB + s;
        const int bbs = ms / M_per;
        const float* xbs = xyz + (size_t)bbs * N_per * 3;
        const float qx = new_xyz[(size_t)ms * 3 + 0];
        const float qy = new_xyz[(size_t)ms * 3 + 1];
        const float qz = new_xyz[(size_t)ms * 3 + 2];
        const float er  = new_xyz_r[ms] + real_t * 5.0f;
        const float er2 = er * er;

        // quarter-split of the UNSCANNED remainder [scan0, N_per)
        const int rem = N_per - scan0;
        const int rb  = scan0 + (int)(((long long)rem * wv) / WPB);
        const int re  = scan0 + (int)(((long long)rem * (wv + 1)) / WPB);

        int c2 = scan_range_deep(xbs, qx, qy, qz, er2, rb, re, lane, lt, sH[wv]);
        if (lane == 0) sC[wv] = (c2 < NS) ? c2 : NS;
        __syncthreads();             // sH/sC ready

        if (threadIdx.x < NS) {      // in-order merge (wave 0 lanes)
            const int j  = threadIdx.x;
            const int cp = sCnt[s];
            const int c0 = sC[0], c1 = sC[1], c2_ = sC[2], c3 = sC[3];
            const int o0 = cp, o1 = o0 + c0, o2 = o1 + c1, o3 = o2 + c2_;
            const int tot = o3 + c3;
            int v = 0;
            if (j < tot) {
                if      (j <  o0) v = sIdx[s][j];
                else if (j <  o1) v = sH[0][j - o0];
                else if (j <  o2) v = sH[1][j - o1];
                else if (j <  o3) v = sH[2][j - o2];
                else              v = sH[3][j - o3];
            }
            int first = 0;
            if      (cp  > 0) first = sIdx[s][0];
            else if (c0  > 0) first = sH[0][0];
            else if (c1  > 0) first = sH[1][0];
            else if (c2_ > 0) first = sH[2][0];
            else if (c3  > 0) first = sH[3][0];
            sM[j] = (tot == 0) ? 0 : ((j < tot) ? v : first);
            if (j == 0) sTot = tot;
        }
        __syncthreads();             // sM/sTot ready

        // 4-wave cooperative epilogue (each wave uses its own sBuf tile)
        write_query_coop(ms, bbs, /*empty=*/(sTot == 0), lane, wv, sM,
                         sBuf + wv * (32 * TSTRIDE),
                         xyz, new_xyz, new_xyz_r, features, real_t, out,
                         N_per, C, M_tot);
        __syncthreads();             // sH/sC/sM/sBuf reusable next straggler
    }
}

extern "C" void kernel_launch(void* const* d_in, const int* in_sizes, int n_in,
                              void* d_out, int out_size, void* d_ws, size_t ws_size,
                              hipStream_t stream) {
    const float* xyz       = (const float*)d_in[0];
    const float* new_xyz   = (const float*)d_in[2];
    const float* new_xyz_r = (const float*)d_in[3];
    const float* features  = (const float*)d_in[5];
    const float* tdec      = (const float*)d_in[6];

    const int B     = in_sizes[1];
    const int N_tot = in_sizes[0] / 3;
    const int M_tot = in_sizes[2] / 3;
    const int C     = in_sizes[5] / N_tot;
    const int N_per = N_tot / B;
    const int M_per = M_tot / B;

    float* out = (float*)d_out;

    const int blocks = (M_tot + WPB - 1) / WPB;
    qgd_F<<<blocks, 256, 0, stream>>>(xyz, new_xyz, new_xyz_r, features,
                                      tdec, out, N_per, M_per, C, M_tot);
}

// Round 9
// 115.664 us; speedup vs baseline: 3.6998x; 1.0234x over previous
//
#include <hip/hip_runtime.h>
#include <math.h>

#define NS 32          // NSAMPLE
#define WPB 4          // waves per block
#define SCAN0 2048     // prefix length scanned by kernel A
#define TSTRIDE 36     // transpose j-stride in dwords (mult of 4 -> b128-aligned)

// ---------------------------------------------------------------------------
// Per-WAVE output epilogue for one query m (round-1/7 proven form, plain
// stores). Wave-internal LDS transpose, XOR-swizzled (2-way banked = free).
// ---------------------------------------------------------------------------
__device__ __forceinline__ void write_query(
    int m, int bb, bool empty, int lane,
    const int* sIdxW, float* sT,
    const float* __restrict__ xyz, const float* __restrict__ new_xyz,
    const float* __restrict__ new_xyz_r, const float* __restrict__ features,
    float real_t, float* __restrict__ out, int N_per, int C, int M_tot)
{
#pragma clang fp contract(off)
    const float* xb = xyz + (size_t)bb * N_per * 3;
    const int    j  = lane & 31;
    const size_t nf_base = (size_t)m * (3 + C) * NS;
    float* wout = out + (size_t)M_tot * (3 + C) * NS;
    float* iout = wout + (size_t)M_tot * NS;

    if (lane < NS) {
        const float qx = new_xyz[(size_t)m * 3 + 0];
        const float qy = new_xyz[(size_t)m * 3 + 1];
        const float qz = new_xyz[(size_t)m * 3 + 2];
        const float r_orig = new_xyz_r[m];
        const int pj = empty ? 0 : sIdxW[j];
        float gx = 0.f, gy = 0.f, gz = 0.f;
        if (!empty) {
            gx = xb[(size_t)pj * 3 + 0] - qx;
            gy = xb[(size_t)pj * 3 + 1] - qy;
            gz = xb[(size_t)pj * 3 + 2] - qz;
        }
        float d2 = gx * gx;
        d2 = d2 + gy * gy;
        d2 = d2 + gz * gz;
        float dist = sqrtf(d2);
        float wt = 1.0f / (1.0f + expf((dist - r_orig) / real_t)); // 1-sigmoid
        out[nf_base + 0 * NS + j] = gx;
        out[nf_base + 1 * NS + j] = gy;
        out[nf_base + 2 * NS + j] = gz;
        wout[(size_t)m * NS + j] = wt;
        iout[(size_t)m * NS + j] = (float)pj;   // f32 buffer; idx exact
    }

    const float* fb = features + (size_t)bb * N_per * C;
    int c0 = 0;
    for (; c0 + 32 <= C; c0 += 32) {
        const int k  = lane & 7;                 // col group (4 channels)
        const int f4 = 4 * (k & 3);              // XOR swizzle
        #pragma unroll
        for (int t = 0; t < 4; ++t) {
            const int r  = 8 * t + (lane >> 3);  // sample slot
            const int pj = empty ? 0 : sIdxW[r];
            float4 v = make_float4(0.f, 0.f, 0.f, 0.f);
            if (!empty) v = *(const float4*)(fb + (size_t)pj * C + c0 + 4 * k);
            const int rs = r ^ f4;
            sT[(4 * k + 0) * TSTRIDE + rs] = v.x;
            sT[(4 * k + 1) * TSTRIDE + rs] = v.y;
            sT[(4 * k + 2) * TSTRIDE + rs] = v.z;
            sT[(4 * k + 3) * TSTRIDE + rs] = v.w;
        }
        // wave-internal LDS dependency: lockstep + lgkmcnt, no barrier
        const int jg = lane & 7;                 // group of 4 samples
        #pragma unroll
        for (int s2 = 0; s2 < 4; ++s2) {
            const int ch = 8 * s2 + (lane >> 3); // channel within pass
            const int jb = (4 * jg) ^ (4 * ((ch >> 2) & 3));
            float4 w = *(const float4*)&sT[ch * TSTRIDE + jb];
            *(float4*)&out[nf_base + (size_t)(3 + c0 + ch) * NS + 4 * jg] = w;
        }
    }
    if (c0 < C) {   // tail for C % 32 != 0 (dead for C=64)
        const int h  = lane >> 5;
        const int pj = empty ? 0 : sIdxW[j];
        const float* frow = fb + (size_t)pj * C;
        for (int c = c0 + h; c < C; c += 2) {
            float v = empty ? 0.f : frow[c];
            out[nf_base + (size_t)(3 + c) * NS + j] = v;
        }
    }
}

// ---------------------------------------------------------------------------
// 4-wave COOPERATIVE epilogue (straggler path, round-7 proven): waves 0..2
// split the 32-channel feature passes (own LDS tile each, no cross-wave
// dependency); wave 3 writes the xyz/weight/idx header + any C%32 tail.
// ---------------------------------------------------------------------------
__device__ __forceinline__ void write_query_coop(
    int m, int bb, bool empty, int lane, int wv,
    const int* sIdxW, float* sT,
    const float* __restrict__ xyz, const float* __restrict__ new_xyz,
    const float* __restrict__ new_xyz_r, const float* __restrict__ features,
    float real_t, float* __restrict__ out, int N_per, int C, int M_tot)
{
#pragma clang fp contract(off)
    const size_t nf_base = (size_t)m * (3 + C) * NS;

    if (wv == 3) {
        const float* xb = xyz + (size_t)bb * N_per * 3;
        const int    j  = lane & 31;
        float* wout = out + (size_t)M_tot * (3 + C) * NS;
        float* iout = wout + (size_t)M_tot * NS;
        if (lane < NS) {
            const float qx = new_xyz[(size_t)m * 3 + 0];
            const float qy = new_xyz[(size_t)m * 3 + 1];
            const float qz = new_xyz[(size_t)m * 3 + 2];
            const float r_orig = new_xyz_r[m];
            const int pj = empty ? 0 : sIdxW[j];
            float gx = 0.f, gy = 0.f, gz = 0.f;
            if (!empty) {
                gx = xb[(size_t)pj * 3 + 0] - qx;
                gy = xb[(size_t)pj * 3 + 1] - qy;
                gz = xb[(size_t)pj * 3 + 2] - qz;
            }
            float d2 = gx * gx;
            d2 = d2 + gy * gy;
            d2 = d2 + gz * gz;
            float dist = sqrtf(d2);
            float wt = 1.0f / (1.0f + expf((dist - r_orig) / real_t));
            out[nf_base + 0 * NS + j] = gx;
            out[nf_base + 1 * NS + j] = gy;
            out[nf_base + 2 * NS + j] = gz;
            wout[(size_t)m * NS + j] = wt;
            iout[(size_t)m * NS + j] = (float)pj;
        }
        const int c0f = (C / 32) * 32;    // C%32 tail (dead for C=64)
        if (c0f < C) {
            const int h  = lane >> 5;
            const int pj = empty ? 0 : sIdxW[j];
            const float* frow = features + (size_t)bb * N_per * C + (size_t)pj * C;
            for (int c = c0f + h; c < C; c += 2) {
                float v = empty ? 0.f : frow[c];
                out[nf_base + (size_t)(3 + c) * NS + j] = v;
            }
        }
        return;
    }

    const float* fb = features + (size_t)bb * N_per * C;
    for (int c0 = 32 * wv; c0 + 32 <= C; c0 += 96) {
        const int k  = lane & 7;
        const int f4 = 4 * (k & 3);
        #pragma unroll
        for (int t = 0; t < 4; ++t) {
            const int r  = 8 * t + (lane >> 3);
            const int pj = empty ? 0 : sIdxW[r];
            float4 v = make_float4(0.f, 0.f, 0.f, 0.f);
            if (!empty) v = *(const float4*)(fb + (size_t)pj * C + c0 + 4 * k);
            const int rs = r ^ f4;
            sT[(4 * k + 0) * TSTRIDE + rs] = v.x;
            sT[(4 * k + 1) * TSTRIDE + rs] = v.y;
            sT[(4 * k + 2) * TSTRIDE + rs] = v.z;
            sT[(4 * k + 3) * TSTRIDE + rs] = v.w;
        }
        const int jg = lane & 7;
        #pragma unroll
        for (int s2 = 0; s2 < 4; ++s2) {
            const int ch = 8 * s2 + (lane >> 3);
            const int jb = (4 * jg) ^ (4 * ((ch >> 2) & 3));
            float4 w = *(const float4*)&sT[ch * TSTRIDE + jb];
            *(float4*)&out[nf_base + (size_t)(3 + c0 + ch) * NS + 4 * jg] = w;
        }
    }
}

// ---------------------------------------------------------------------------
// Wave-level in-index-order ball scan, 256-pt chunks (phase-1 proven form).
// ---------------------------------------------------------------------------
__device__ __forceinline__ int scan_range(
    const float* __restrict__ xb, float qx, float qy, float qz, float er2,
    int rb, int re, int lane, unsigned long long lt, int* hits)
{
#pragma clang fp contract(off)          // keep d2 < r^2 bit-exact vs numpy
    int cnt = 0;
    for (int base = rb; base < re; base += 256) {
        float d2k[4];
        #pragma unroll
        for (int k = 0; k < 4; ++k) {
            int p = base + k * 64 + lane;
            int pc = (p < re) ? p : (re - 1);
            const float* pp = xb + (size_t)pc * 3;
            float dx = pp[0] - qx, dy = pp[1] - qy, dz = pp[2] - qz;
            float d2 = dx * dx;
            d2 = d2 + dy * dy;          // numpy left-fold order
            d2 = d2 + dz * dz;
            d2k[k] = (p < re) ? d2 : 1e30f;
        }
        #pragma unroll
        for (int k = 0; k < 4; ++k) {
            bool hit = d2k[k] < er2;    // strict <
            unsigned long long msk = __ballot(hit);
            if (hit) {
                int slot = cnt + (int)__popcll(msk & lt);
                if (slot < NS) hits[slot] = base + k * 64 + lane;
            }
            cnt += (int)__popcll(msk);  // wave-uniform
        }
        if (cnt >= NS) break;           // wave-uniform
    }
    return cnt;
}

// ---------------------------------------------------------------------------
// Deep variant for straggler rescans (round-7 proven): 512-pt chunks, 24
// loads in flight per chain step; stragglers rarely early-exit so the
// coarser exit granularity is free and the latency chain halves.
// ---------------------------------------------------------------------------
__device__ __forceinline__ int scan_range_deep(
    const float* __restrict__ xb, float qx, float qy, float qz, float er2,
    int rb, int re, int lane, unsigned long long lt, int* hits)
{
#pragma clang fp contract(off)
    int cnt = 0;
    for (int base = rb; base < re; base += 512) {
        float d2k[8];
        #pragma unroll
        for (int k = 0; k < 8; ++k) {
            int p = base + k * 64 + lane;
            int pc = (p < re) ? p : (re - 1);
            const float* pp = xb + (size_t)pc * 3;
            float dx = pp[0] - qx, dy = pp[1] - qy, dz = pp[2] - qz;
            float d2 = dx * dx;
            d2 = d2 + dy * dy;          // numpy left-fold order
            d2 = d2 + dz * dz;
            d2k[k] = (p < re) ? d2 : 1e30f;
        }
        #pragma unroll
        for (int k = 0; k < 8; ++k) {
            bool hit = d2k[k] < er2;    // strict <
            unsigned long long msk = __ballot(hit);
            if (hit) {
                int slot = cnt + (int)__popcll(msk & lt);
                if (slot < NS) hits[slot] = base + k * 64 + lane;
            }
            cnt += (int)__popcll(msk);  // wave-uniform
        }
        if (cnt >= NS) break;           // wave-uniform
    }
    return cnt;
}

// ---------------------------------------------------------------------------
// Kernel A (round-0/7 proven): per-wave prefix ball-query (first SCAN0
// points). Queries reaching NS hits write ALL outputs immediately (per-wave
// epilogue, no barriers anywhere -> waves fully decoupled). cnt<NS ->
// straggler list (atomicAdd slot + atomicExch publish, R0-proven handoff).
// ---------------------------------------------------------------------------
__global__ __launch_bounds__(256) void qgd_A(
    const float* __restrict__ xyz, const float* __restrict__ new_xyz,
    const float* __restrict__ new_xyz_r, const float* __restrict__ features,
    const float* __restrict__ tdec, float* __restrict__ out,
    int* __restrict__ counter, int* __restrict__ list,
    int N_per, int M_per, int C, int M_tot)
{
#pragma clang fp contract(off)
    __shared__ __align__(16) float sBuf[WPB * 32 * TSTRIDE];
    __shared__ int sIdx[WPB][NS];

    const int lane = threadIdx.x & 63;
    const int wv   = threadIdx.x >> 6;
    const int m    = blockIdx.x * WPB + wv;
    if (m >= M_tot) return;             // wave-uniform; kernel is barrier-free

    const int bb = m / M_per;
    const float* xb = xyz + (size_t)bb * N_per * 3;
    const float qx = new_xyz[(size_t)m * 3 + 0];
    const float qy = new_xyz[(size_t)m * 3 + 1];
    const float qz = new_xyz[(size_t)m * 3 + 2];
    const float real_t = 0.1f * tdec[0];
    const float er  = new_xyz_r[m] + real_t * 5.0f;
    const float er2 = er * er;
    const unsigned long long lt = (1ull << lane) - 1ull;
    const int scan0 = (SCAN0 < N_per) ? SCAN0 : N_per;

    int cnt = scan_range(xb, qx, qy, qz, er2, 0, scan0, lane, lt, sIdx[wv]);

    if (cnt >= NS) {
        write_query(m, bb, /*empty=*/false, lane, sIdx[wv],
                    sBuf + wv * (32 * TSTRIDE),
                    xyz, new_xyz, new_xyz_r, features, real_t, out,
                    N_per, C, M_tot);
    } else if (lane == 0) {
        int pos = atomicAdd(counter, 1);
        atomicExch(&list[pos], m);      // device-visible publish (R0-proven)
    }
}

// ---------------------------------------------------------------------------
// Kernel B: straggler full rescan + write. Grid-stride, ONE straggler per
// block per round (2048 blocks >= typical nstrag -> single balanced round,
// no serial per-block tail). 4 waves scan disjoint quarters of [0, N_per)
// with deep 512-pt chunks; in-order LDS merge gives exact first-NS
// semantics; 4-wave cooperative epilogue.
// ---------------------------------------------------------------------------
__global__ __launch_bounds__(256) void qgd_B(
    const float* __restrict__ xyz, const float* __restrict__ new_xyz,
    const float* __restrict__ new_xyz_r, const float* __restrict__ features,
    const float* __restrict__ tdec, float* __restrict__ out,
    const int* __restrict__ counter, const int* __restrict__ list,
    int N_per, int M_per, int C, int M_tot)
{
#pragma clang fp contract(off)
    __shared__ __align__(16) float sBuf[WPB * 32 * TSTRIDE];
    __shared__ int sH[WPB][NS];
    __shared__ int sC[WPB];
    __shared__ int sM[NS];
    __shared__ int sTot;

    const int lane = threadIdx.x & 63;
    const int wv   = threadIdx.x >> 6;
    const int nstrag = *counter;
    const unsigned long long lt = (1ull << lane) - 1ull;
    const float real_t = 0.1f * tdec[0];

    for (int it = blockIdx.x; it < nstrag; it += gridDim.x) {
        const int mq  = list[it];
        const int bbs = mq / M_per;
        const float* xbs = xyz + (size_t)bbs * N_per * 3;
        const float qx = new_xyz[(size_t)mq * 3 + 0];
        const float qy = new_xyz[(size_t)mq * 3 + 1];
        const float qz = new_xyz[(size_t)mq * 3 + 2];
        const float er  = new_xyz_r[mq] + real_t * 5.0f;
        const float er2 = er * er;

        // quarter-split full rescan [0, N_per): exact first-NS via merge
        const int rb = (int)(((long long)N_per * wv) / WPB);
        const int re = (int)(((long long)N_per * (wv + 1)) / WPB);
        int c2 = scan_range_deep(xbs, qx, qy, qz, er2, rb, re, lane, lt,
                                 sH[wv]);
        if (lane == 0) sC[wv] = (c2 < NS) ? c2 : NS;
        __syncthreads();                 // sH/sC ready

        if (threadIdx.x < NS) {          // in-order merge (wave 0 lanes)
            const int j  = threadIdx.x;
            const int c0 = sC[0], c1 = sC[1], c2_ = sC[2], c3 = sC[3];
            const int o1 = c0, o2 = c0 + c1, o3 = o2 + c2_;
            const int tot = o3 + c3;
            int v = 0;
            if (j < tot) {
                if      (j >= o3) v = sH[3][j - o3];
                else if (j >= o2) v = sH[2][j - o2];
                else if (j >= o1) v = sH[1][j - o1];
                else              v = sH[0][j];
            }
            int first = 0;
            if      (c0  > 0) first = sH[0][0];
            else if (c1  > 0) first = sH[1][0];
            else if (c2_ > 0) first = sH[2][0];
            else if (c3  > 0) first = sH[3][0];
            sM[j] = (tot == 0) ? 0 : ((j < tot) ? v : first);
            if (j == 0) sTot = tot;
        }
        __syncthreads();                 // sM/sTot ready

        write_query_coop(mq, bbs, /*empty=*/(sTot == 0), lane, wv, sM,
                         sBuf + wv * (32 * TSTRIDE),
                         xyz, new_xyz, new_xyz_r, features, real_t, out,
                         N_per, C, M_tot);
        __syncthreads();                 // sH/sC/sM/sBuf reusable next iter
    }
}

extern "C" void kernel_launch(void* const* d_in, const int* in_sizes, int n_in,
                              void* d_out, int out_size, void* d_ws, size_t ws_size,
                              hipStream_t stream) {
    const float* xyz       = (const float*)d_in[0];
    const float* new_xyz   = (const float*)d_in[2];
    const float* new_xyz_r = (const float*)d_in[3];
    const float* features  = (const float*)d_in[5];
    const float* tdec      = (const float*)d_in[6];

    const int B     = in_sizes[1];
    const int N_tot = in_sizes[0] / 3;
    const int M_tot = in_sizes[2] / 3;
    const int C     = in_sizes[5] / N_tot;
    const int N_per = N_tot / B;
    const int M_per = M_tot / B;

    float* out     = (float*)d_out;
    int*   counter = (int*)d_ws;
    int*   list    = (int*)d_ws + 4;    // 16B offset; needs (M_tot+4)*4 bytes

    hipMemsetAsync(counter, 0, sizeof(int), stream);

    const int blocksA = (M_tot + WPB - 1) / WPB;
    qgd_A<<<blocksA, 256, 0, stream>>>(xyz, new_xyz, new_xyz_r, features,
                                       tdec, out, counter, list,
                                       N_per, M_per, C, M_tot);
    qgd_B<<<2048, 256, 0, stream>>>(xyz, new_xyz, new_xyz_r, features,
                                    tdec, out, counter, list,
                                    N_per, M_per, C, M_tot);
}

// Round 10
// 112.819 us; speedup vs baseline: 3.7931x; 1.0252x over previous
//
#include <hip/hip_runtime.h>
#include <math.h>

#define NS 32          // NSAMPLE
#define WPB 4          // waves per block
#define SCAN0 2048     // prefix length scanned by kernel A
#define TSTRIDE 36     // transpose j-stride in dwords (mult of 4 -> b128-aligned)
#define NXCD 8         // MI355X XCD count

// ---------------------------------------------------------------------------
// Per-WAVE output epilogue for one query m (round-1/7 proven form, plain
// stores). Wave-internal LDS transpose, XOR-swizzled (2-way banked = free).
// ---------------------------------------------------------------------------
__device__ __forceinline__ void write_query(
    int m, int bb, bool empty, int lane,
    const int* sIdxW, float* sT,
    const float* __restrict__ xyz, const float* __restrict__ new_xyz,
    const float* __restrict__ new_xyz_r, const float* __restrict__ features,
    float real_t, float* __restrict__ out, int N_per, int C, int M_tot)
{
#pragma clang fp contract(off)
    const float* xb = xyz + (size_t)bb * N_per * 3;
    const int    j  = lane & 31;
    const size_t nf_base = (size_t)m * (3 + C) * NS;
    float* wout = out + (size_t)M_tot * (3 + C) * NS;
    float* iout = wout + (size_t)M_tot * NS;

    if (lane < NS) {
        const float qx = new_xyz[(size_t)m * 3 + 0];
        const float qy = new_xyz[(size_t)m * 3 + 1];
        const float qz = new_xyz[(size_t)m * 3 + 2];
        const float r_orig = new_xyz_r[m];
        const int pj = empty ? 0 : sIdxW[j];
        float gx = 0.f, gy = 0.f, gz = 0.f;
        if (!empty) {
            gx = xb[(size_t)pj * 3 + 0] - qx;
            gy = xb[(size_t)pj * 3 + 1] - qy;
            gz = xb[(size_t)pj * 3 + 2] - qz;
        }
        float d2 = gx * gx;
        d2 = d2 + gy * gy;
        d2 = d2 + gz * gz;
        float dist = sqrtf(d2);
        float wt = 1.0f / (1.0f + expf((dist - r_orig) / real_t)); // 1-sigmoid
        out[nf_base + 0 * NS + j] = gx;
        out[nf_base + 1 * NS + j] = gy;
        out[nf_base + 2 * NS + j] = gz;
        wout[(size_t)m * NS + j] = wt;
        iout[(size_t)m * NS + j] = (float)pj;   // f32 buffer; idx exact
    }

    const float* fb = features + (size_t)bb * N_per * C;
    int c0 = 0;
    for (; c0 + 32 <= C; c0 += 32) {
        const int k  = lane & 7;                 // col group (4 channels)
        const int f4 = 4 * (k & 3);              // XOR swizzle
        #pragma unroll
        for (int t = 0; t < 4; ++t) {
            const int r  = 8 * t + (lane >> 3);  // sample slot
            const int pj = empty ? 0 : sIdxW[r];
            float4 v = make_float4(0.f, 0.f, 0.f, 0.f);
            if (!empty) v = *(const float4*)(fb + (size_t)pj * C + c0 + 4 * k);
            const int rs = r ^ f4;
            sT[(4 * k + 0) * TSTRIDE + rs] = v.x;
            sT[(4 * k + 1) * TSTRIDE + rs] = v.y;
            sT[(4 * k + 2) * TSTRIDE + rs] = v.z;
            sT[(4 * k + 3) * TSTRIDE + rs] = v.w;
        }
        // wave-internal LDS dependency: lockstep + lgkmcnt, no barrier
        const int jg = lane & 7;                 // group of 4 samples
        #pragma unroll
        for (int s2 = 0; s2 < 4; ++s2) {
            const int ch = 8 * s2 + (lane >> 3); // channel within pass
            const int jb = (4 * jg) ^ (4 * ((ch >> 2) & 3));
            float4 w = *(const float4*)&sT[ch * TSTRIDE + jb];
            *(float4*)&out[nf_base + (size_t)(3 + c0 + ch) * NS + 4 * jg] = w;
        }
    }
    if (c0 < C) {   // tail for C % 32 != 0 (dead for C=64)
        const int h  = lane >> 5;
        const int pj = empty ? 0 : sIdxW[j];
        const float* frow = fb + (size_t)pj * C;
        for (int c = c0 + h; c < C; c += 2) {
            float v = empty ? 0.f : frow[c];
            out[nf_base + (size_t)(3 + c) * NS + j] = v;
        }
    }
}

// ---------------------------------------------------------------------------
// 4-wave COOPERATIVE epilogue (straggler path, round-7 proven): waves 0..2
// split the 32-channel feature passes (own LDS tile each, no cross-wave
// dependency); wave 3 writes the xyz/weight/idx header + any C%32 tail.
// ---------------------------------------------------------------------------
__device__ __forceinline__ void write_query_coop(
    int m, int bb, bool empty, int lane, int wv,
    const int* sIdxW, float* sT,
    const float* __restrict__ xyz, const float* __restrict__ new_xyz,
    const float* __restrict__ new_xyz_r, const float* __restrict__ features,
    float real_t, float* __restrict__ out, int N_per, int C, int M_tot)
{
#pragma clang fp contract(off)
    const size_t nf_base = (size_t)m * (3 + C) * NS;

    if (wv == 3) {
        const float* xb = xyz + (size_t)bb * N_per * 3;
        const int    j  = lane & 31;
        float* wout = out + (size_t)M_tot * (3 + C) * NS;
        float* iout = wout + (size_t)M_tot * NS;
        if (lane < NS) {
            const float qx = new_xyz[(size_t)m * 3 + 0];
            const float qy = new_xyz[(size_t)m * 3 + 1];
            const float qz = new_xyz[(size_t)m * 3 + 2];
            const float r_orig = new_xyz_r[m];
            const int pj = empty ? 0 : sIdxW[j];
            float gx = 0.f, gy = 0.f, gz = 0.f;
            if (!empty) {
                gx = xb[(size_t)pj * 3 + 0] - qx;
                gy = xb[(size_t)pj * 3 + 1] - qy;
                gz = xb[(size_t)pj * 3 + 2] - qz;
            }
            float d2 = gx * gx;
            d2 = d2 + gy * gy;
            d2 = d2 + gz * gz;
            float dist = sqrtf(d2);
            float wt = 1.0f / (1.0f + expf((dist - r_orig) / real_t));
            out[nf_base + 0 * NS + j] = gx;
            out[nf_base + 1 * NS + j] = gy;
            out[nf_base + 2 * NS + j] = gz;
            wout[(size_t)m * NS + j] = wt;
            iout[(size_t)m * NS + j] = (float)pj;
        }
        const int c0f = (C / 32) * 32;    // C%32 tail (dead for C=64)
        if (c0f < C) {
            const int h  = lane >> 5;
            const int pj = empty ? 0 : sIdxW[j];
            const float* frow = features + (size_t)bb * N_per * C + (size_t)pj * C;
            for (int c = c0f + h; c < C; c += 2) {
                float v = empty ? 0.f : frow[c];
                out[nf_base + (size_t)(3 + c) * NS + j] = v;
            }
        }
        return;
    }

    const float* fb = features + (size_t)bb * N_per * C;
    for (int c0 = 32 * wv; c0 + 32 <= C; c0 += 96) {
        const int k  = lane & 7;
        const int f4 = 4 * (k & 3);
        #pragma unroll
        for (int t = 0; t < 4; ++t) {
            const int r  = 8 * t + (lane >> 3);
            const int pj = empty ? 0 : sIdxW[r];
            float4 v = make_float4(0.f, 0.f, 0.f, 0.f);
            if (!empty) v = *(const float4*)(fb + (size_t)pj * C + c0 + 4 * k);
            const int rs = r ^ f4;
            sT[(4 * k + 0) * TSTRIDE + rs] = v.x;
            sT[(4 * k + 1) * TSTRIDE + rs] = v.y;
            sT[(4 * k + 2) * TSTRIDE + rs] = v.z;
            sT[(4 * k + 3) * TSTRIDE + rs] = v.w;
        }
        const int jg = lane & 7;
        #pragma unroll
        for (int s2 = 0; s2 < 4; ++s2) {
            const int ch = 8 * s2 + (lane >> 3);
            const int jb = (4 * jg) ^ (4 * ((ch >> 2) & 3));
            float4 w = *(const float4*)&sT[ch * TSTRIDE + jb];
            *(float4*)&out[nf_base + (size_t)(3 + c0 + ch) * NS + 4 * jg] = w;
        }
    }
}

// ---------------------------------------------------------------------------
// Wave-level in-index-order ball scan, 256-pt chunks (phase-1 proven form).
// ---------------------------------------------------------------------------
__device__ __forceinline__ int scan_range(
    const float* __restrict__ xb, float qx, float qy, float qz, float er2,
    int rb, int re, int lane, unsigned long long lt, int* hits)
{
#pragma clang fp contract(off)          // keep d2 < r^2 bit-exact vs numpy
    int cnt = 0;
    for (int base = rb; base < re; base += 256) {
        float d2k[4];
        #pragma unroll
        for (int k = 0; k < 4; ++k) {
            int p = base + k * 64 + lane;
            int pc = (p < re) ? p : (re - 1);
            const float* pp = xb + (size_t)pc * 3;
            float dx = pp[0] - qx, dy = pp[1] - qy, dz = pp[2] - qz;
            float d2 = dx * dx;
            d2 = d2 + dy * dy;          // numpy left-fold order
            d2 = d2 + dz * dz;
            d2k[k] = (p < re) ? d2 : 1e30f;
        }
        #pragma unroll
        for (int k = 0; k < 4; ++k) {
            bool hit = d2k[k] < er2;    // strict <
            unsigned long long msk = __ballot(hit);
            if (hit) {
                int slot = cnt + (int)__popcll(msk & lt);
                if (slot < NS) hits[slot] = base + k * 64 + lane;
            }
            cnt += (int)__popcll(msk);  // wave-uniform
        }
        if (cnt >= NS) break;           // wave-uniform
    }
    return cnt;
}

// ---------------------------------------------------------------------------
// Deep variant for straggler rescans (round-7 proven): 512-pt chunks, 24
// loads in flight per chain step; stragglers rarely early-exit so the
// coarser exit granularity is free and the latency chain halves.
// ---------------------------------------------------------------------------
__device__ __forceinline__ int scan_range_deep(
    const float* __restrict__ xb, float qx, float qy, float qz, float er2,
    int rb, int re, int lane, unsigned long long lt, int* hits)
{
#pragma clang fp contract(off)
    int cnt = 0;
    for (int base = rb; base < re; base += 512) {
        float d2k[8];
        #pragma unroll
        for (int k = 0; k < 8; ++k) {
            int p = base + k * 64 + lane;
            int pc = (p < re) ? p : (re - 1);
            const float* pp = xb + (size_t)pc * 3;
            float dx = pp[0] - qx, dy = pp[1] - qy, dz = pp[2] - qz;
            float d2 = dx * dx;
            d2 = d2 + dy * dy;          // numpy left-fold order
            d2 = d2 + dz * dz;
            d2k[k] = (p < re) ? d2 : 1e30f;
        }
        #pragma unroll
        for (int k = 0; k < 8; ++k) {
            bool hit = d2k[k] < er2;    // strict <
            unsigned long long msk = __ballot(hit);
            if (hit) {
                int slot = cnt + (int)__popcll(msk & lt);
                if (slot < NS) hits[slot] = base + k * 64 + lane;
            }
            cnt += (int)__popcll(msk);  // wave-uniform
        }
        if (cnt >= NS) break;           // wave-uniform
    }
    return cnt;
}

// ---------------------------------------------------------------------------
// Kernel A (round-9 proven + XCD swizzle): per-wave prefix ball-query (first
// SCAN0 points). Queries reaching NS hits write ALL outputs immediately
// (per-wave epilogue, no barriers -> waves fully decoupled). cnt<NS ->
// straggler list (atomicAdd slot + atomicExch publish, R0-proven handoff).
// XCD swizzle (bijective, grid%8==0): XCDs 0-3 serve batch 0, XCDs 4-7 serve
// batch 1 -> per-XCD feature gather working set = 4 MB = exactly one XCD L2
// (default round-robin puts BOTH 4 MB batch tables on every XCD -> thrash ->
// gathers at LLC latency; FETCH_SIZE can't see this, only latency does).
// ---------------------------------------------------------------------------
__global__ __launch_bounds__(256) void qgd_A(
    const float* __restrict__ xyz, const float* __restrict__ new_xyz,
    const float* __restrict__ new_xyz_r, const float* __restrict__ features,
    const float* __restrict__ tdec, float* __restrict__ out,
    int* __restrict__ counter, int* __restrict__ list,
    int N_per, int M_per, int C, int M_tot)
{
#pragma clang fp contract(off)
    __shared__ __align__(16) float sBuf[WPB * 32 * TSTRIDE];
    __shared__ int sIdx[WPB][NS];

    const int lane = threadIdx.x & 63;
    const int wv   = threadIdx.x >> 6;
    // XCD-aware bijective swizzle (identity when grid not divisible by 8)
    const int bid = ((gridDim.x & (NXCD - 1)) == 0)
                        ? ((blockIdx.x & (NXCD - 1)) * (gridDim.x >> 3) +
                           (blockIdx.x >> 3))
                        : blockIdx.x;
    const int m    = bid * WPB + wv;
    if (m >= M_tot) return;             // wave-uniform; kernel is barrier-free

    const int bb = m / M_per;
    const float* xb = xyz + (size_t)bb * N_per * 3;
    const float qx = new_xyz[(size_t)m * 3 + 0];
    const float qy = new_xyz[(size_t)m * 3 + 1];
    const float qz = new_xyz[(size_t)m * 3 + 2];
    const float real_t = 0.1f * tdec[0];
    const float er  = new_xyz_r[m] + real_t * 5.0f;
    const float er2 = er * er;
    const unsigned long long lt = (1ull << lane) - 1ull;
    const int scan0 = (SCAN0 < N_per) ? SCAN0 : N_per;

    int cnt = scan_range(xb, qx, qy, qz, er2, 0, scan0, lane, lt, sIdx[wv]);

    if (cnt >= NS) {
        write_query(m, bb, /*empty=*/false, lane, sIdx[wv],
                    sBuf + wv * (32 * TSTRIDE),
                    xyz, new_xyz, new_xyz_r, features, real_t, out,
                    N_per, C, M_tot);
    } else if (lane == 0) {
        int pos = atomicAdd(counter, 1);
        atomicExch(&list[pos], m);      // device-visible publish (R0-proven)
    }
}

// ---------------------------------------------------------------------------
// Kernel B (round-9 proven): straggler full rescan + write. Grid-stride, ONE
// straggler per block per round (2048 blocks >= typical nstrag -> single
// balanced round). 4 waves scan disjoint quarters of [0, N_per) with deep
// 512-pt chunks; in-order LDS merge gives exact first-NS semantics; 4-wave
// cooperative epilogue. (No swizzle: list order is atomic-scrambled anyway.)
// ---------------------------------------------------------------------------
__global__ __launch_bounds__(256) void qgd_B(
    const float* __restrict__ xyz, const float* __restrict__ new_xyz,
    const float* __restrict__ new_xyz_r, const float* __restrict__ features,
    const float* __restrict__ tdec, float* __restrict__ out,
    const int* __restrict__ counter, const int* __restrict__ list,
    int N_per, int M_per, int C, int M_tot)
{
#pragma clang fp contract(off)
    __shared__ __align__(16) float sBuf[WPB * 32 * TSTRIDE];
    __shared__ int sH[WPB][NS];
    __shared__ int sC[WPB];
    __shared__ int sM[NS];
    __shared__ int sTot;

    const int lane = threadIdx.x & 63;
    const int wv   = threadIdx.x >> 6;
    const int nstrag = *counter;
    const unsigned long long lt = (1ull << lane) - 1ull;
    const float real_t = 0.1f * tdec[0];

    for (int it = blockIdx.x; it < nstrag; it += gridDim.x) {
        const int mq  = list[it];
        const int bbs = mq / M_per;
        const float* xbs = xyz + (size_t)bbs * N_per * 3;
        const float qx = new_xyz[(size_t)mq * 3 + 0];
        const float qy = new_xyz[(size_t)mq * 3 + 1];
        const float qz = new_xyz[(size_t)mq * 3 + 2];
        const float er  = new_xyz_r[mq] + real_t * 5.0f;
        const float er2 = er * er;

        // quarter-split full rescan [0, N_per): exact first-NS via merge
        const int rb = (int)(((long long)N_per * wv) / WPB);
        const int re = (int)(((long long)N_per * (wv + 1)) / WPB);
        int c2 = scan_range_deep(xbs, qx, qy, qz, er2, rb, re, lane, lt,
                                 sH[wv]);
        if (lane == 0) sC[wv] = (c2 < NS) ? c2 : NS;
        __syncthreads();                 // sH/sC ready

        if (threadIdx.x < NS) {          // in-order merge (wave 0 lanes)
            const int j  = threadIdx.x;
            const int c0 = sC[0], c1 = sC[1], c2_ = sC[2], c3 = sC[3];
            const int o1 = c0, o2 = c0 + c1, o3 = o2 + c2_;
            const int tot = o3 + c3;
            int v = 0;
            if (j < tot) {
                if      (j >= o3) v = sH[3][j - o3];
                else if (j >= o2) v = sH[2][j - o2];
                else if (j >= o1) v = sH[1][j - o1];
                else              v = sH[0][j];
            }
            int first = 0;
            if      (c0  > 0) first = sH[0][0];
            else if (c1  > 0) first = sH[1][0];
            else if (c2_ > 0) first = sH[2][0];
            else if (c3  > 0) first = sH[3][0];
            sM[j] = (tot == 0) ? 0 : ((j < tot) ? v : first);
            if (j == 0) sTot = tot;
        }
        __syncthreads();                 // sM/sTot ready

        write_query_coop(mq, bbs, /*empty=*/(sTot == 0), lane, wv, sM,
                         sBuf + wv * (32 * TSTRIDE),
                         xyz, new_xyz, new_xyz_r, features, real_t, out,
                         N_per, C, M_tot);
        __syncthreads();                 // sH/sC/sM/sBuf reusable next iter
    }
}

extern "C" void kernel_launch(void* const* d_in, const int* in_sizes, int n_in,
                              void* d_out, int out_size, void* d_ws, size_t ws_size,
                              hipStream_t stream) {
    const float* xyz       = (const float*)d_in[0];
    const float* new_xyz   = (const float*)d_in[2];
    const float* new_xyz_r = (const float*)d_in[3];
    const float* features  = (const float*)d_in[5];
    const float* tdec      = (const float*)d_in[6];

    const int B     = in_sizes[1];
    const int N_tot = in_sizes[0] / 3;
    const int M_tot = in_sizes[2] / 3;
    const int C     = in_sizes[5] / N_tot;
    const int N_per = N_tot / B;
    const int M_per = M_tot / B;

    float* out     = (float*)d_out;
    int*   counter = (int*)d_ws;
    int*   list    = (int*)d_ws + 4;    // 16B offset; needs (M_tot+4)*4 bytes

    hipMemsetAsync(counter, 0, sizeof(int), stream);

    const int blocksA = (M_tot + WPB - 1) / WPB;
    qgd_A<<<blocksA, 256, 0, stream>>>(xyz, new_xyz, new_xyz_r, features,
                                       tdec, out, counter, list,
                                       N_per, M_per, C, M_tot);
    qgd_B<<<2048, 256, 0, stream>>>(xyz, new_xyz, new_xyz_r, features,
                                    tdec, out, counter, list,
                                    N_per, M_per, C, M_tot);
}